// Round 6
// baseline (105.611 us; speedup 1.0000x reference)
//
#include <hip/hip_runtime.h>
#include <math.h>

#define B_ 8
#define C_ 128
#define N_ 64
#define T_ 512
#define H_ 4
#define D_ 32
#define OUT_ 128
#define E_ 256
#define EP_ 320   // E + N self-loops
#define NEG_SLOPE 0.2f
#define BN_EPS 1e-5f

// ---- setup: wa[c][8] = W·att, edge lists, in-CSR (by dst) and out-CSR (by src)
__global__ void setup_kernel(const float* __restrict__ W,
                             const float* __restrict__ att_src,
                             const float* __restrict__ att_dst,
                             const int* __restrict__ edge_index,
                             float* __restrict__ wa,
                             int* __restrict__ esrc_g, int* __restrict__ edst_g,
                             int* __restrict__ iOff_g, int* __restrict__ iEid_g,
                             int* __restrict__ oOff_g, int* __restrict__ oEid_g) {
  __shared__ int icnt[N_], ibase[N_ + 1], ifill[N_];
  __shared__ int ocnt[N_], obase[N_ + 1], ofill[N_];
  __shared__ int esrc[EP_], edst[EP_];
  int tid = threadIdx.x;

  for (int idx = tid; idx < C_ * 8; idx += blockDim.x) {
    int c = idx >> 3, j = idx & 7, h = j & 3;
    const float* att = (j < 4) ? att_src : att_dst;
    float s = 0.f;
    for (int d = 0; d < D_; ++d)
      s += W[(c * H_ + h) * D_ + d] * att[h * D_ + d];
    wa[idx] = s;
  }
  if (tid < N_) { icnt[tid] = 0; ifill[tid] = 0; ocnt[tid] = 0; ofill[tid] = 0; }
  __syncthreads();
  for (int e = tid; e < EP_; e += blockDim.x) {
    int s, d;
    if (e < E_) { s = edge_index[e]; d = edge_index[E_ + e]; }
    else        { s = e - E_;        d = e - E_; }
    esrc[e] = s; edst[e] = d;
    atomicAdd(&icnt[d], 1);
    atomicAdd(&ocnt[s], 1);
  }
  __syncthreads();
  if (tid == 0) {
    int ai = 0, ao = 0;
    for (int n = 0; n < N_; ++n) {
      ibase[n] = ai; ai += icnt[n];
      obase[n] = ao; ao += ocnt[n];
    }
    ibase[N_] = ai; obase[N_] = ao;
  }
  __syncthreads();
  if (tid <= N_) { iOff_g[tid] = ibase[tid]; oOff_g[tid] = obase[tid]; }
  for (int e = tid; e < EP_; e += blockDim.x) {
    esrc_g[e] = esrc[e]; edst_g[e] = edst[e];
    int d = edst[e];
    int pi = ibase[d] + atomicAdd(&ifill[d], 1);
    iEid_g[pi] = e;
    int s = esrc[e];
    int po = obase[s] + atomicAdd(&ofill[s], 1);
    oEid_g[po] = e;
  }
}

// ---- kernel A: a[b][n][j][t] = sum_c x[b][c][n][t] * wa[c][j] ------------------
// grid = B*N*2 = 1024 (4 blocks/CU, 16 waves/CU). Each wave reduces 32 c's with
// float4 loads unrolled 8 (8 KB outstanding/wave); LDS reduce across 4 waves.
__global__ __launch_bounds__(256, 4)
void proj_kernel(const float* __restrict__ x,
                 const float* __restrict__ wa_g,
                 float* __restrict__ a_ws) {
  __shared__ float wal[C_ * 8];
  __shared__ float4 red4[4 * 8 * 64];   // [cg][j][tq]  32 KB
  const int tid = threadIdx.x;
  const int bid = blockIdx.x;
  const int half = bid & 1;
  const int n = (bid >> 1) & 63;
  const int b = bid >> 7;

  for (int i = tid; i < C_ * 8; i += 256) wal[i] = wa_g[i];
  __syncthreads();

  const int cg = tid >> 6, tq = tid & 63;
  const float* xp = x + ((size_t)(b * C_) * N_ + n) * T_ + half * 256 + tq * 4;
  float4 acc[8];
#pragma unroll
  for (int j = 0; j < 8; ++j) { acc[j].x = 0.f; acc[j].y = 0.f; acc[j].z = 0.f; acc[j].w = 0.f; }
#pragma unroll 8
  for (int k = 0; k < 32; ++k) {
    int c = cg + 4 * k;
    float4 xv = *reinterpret_cast<const float4*>(xp + (size_t)c * (N_ * T_));
#pragma unroll
    for (int j = 0; j < 8; ++j) {
      float wj = wal[c * 8 + j];
      acc[j].x = fmaf(xv.x, wj, acc[j].x);
      acc[j].y = fmaf(xv.y, wj, acc[j].y);
      acc[j].z = fmaf(xv.z, wj, acc[j].z);
      acc[j].w = fmaf(xv.w, wj, acc[j].w);
    }
  }
#pragma unroll
  for (int j = 0; j < 8; ++j) red4[(cg * 8 + j) * 64 + tq] = acc[j];
  __syncthreads();

#pragma unroll
  for (int rep = 0; rep < 2; ++rep) {
    int ss = tid + rep * 256;
    int j = ss >> 6, tq2 = ss & 63;
    float4 v0 = red4[(0 * 8 + j) * 64 + tq2];
    float4 v1 = red4[(1 * 8 + j) * 64 + tq2];
    float4 v2 = red4[(2 * 8 + j) * 64 + tq2];
    float4 v3 = red4[(3 * 8 + j) * 64 + tq2];
    float4 r;
    r.x = (v0.x + v1.x) + (v2.x + v3.x);
    r.y = (v0.y + v1.y) + (v2.y + v3.y);
    r.z = (v0.z + v1.z) + (v2.z + v3.z);
    r.w = (v0.w + v1.w) + (v2.w + v3.w);
    *reinterpret_cast<float4*>(
        a_ws + ((size_t)(b * N_ + n) * 8 + j) * T_ + half * 256 + tq2 * 4) = r;
  }
}

// ---- kernel B1: segment softmax -> w[b][n][h][t], atomic-free ------------------
// grid = B*(T/16) = 256, block = 256 (1 block/CU; LDS ~136 KB)
__global__ __launch_bounds__(256, 1)
void weights_kernel(const float* __restrict__ a_ws,
                    const int* __restrict__ esrc_g, const int* __restrict__ edst_g,
                    const int* __restrict__ iOff_g, const int* __restrict__ iEid_g,
                    const int* __restrict__ oOff_g, const int* __restrict__ oEid_g,
                    float* __restrict__ w_ws) {
  __shared__ float a_l[8][64][16];    // [j][n][t]  32 KB
  __shared__ float4 sc[EP_][16];      // scores -> alpha, 80 KB
  __shared__ float w_l[N_ * 64];      // [n][h][16]  16 KB
  __shared__ int eS[EP_], eD[EP_];
  __shared__ int iOff[N_ + 1], iEid[EP_], oOff[N_ + 1], oEid[EP_];
  int tid = threadIdx.x;
  int b  = blockIdx.x >> 5;
  int t0 = (blockIdx.x & 31) * 16;

  for (int i = tid; i < EP_; i += 256) {
    eS[i] = esrc_g[i]; eD[i] = edst_g[i];
    iEid[i] = iEid_g[i]; oEid[i] = oEid_g[i];
  }
  if (tid <= N_) { iOff[tid] = iOff_g[tid]; oOff[tid] = oOff_g[tid]; }
  for (int r = tid; r < 512; r += 256) {       // 512 rows of 16 floats
    int n = r >> 3, j = r & 7;
    const float4* src = reinterpret_cast<const float4*>(
        a_ws + (((size_t)b * N_ + n) * 8 + j) * T_ + t0);
    float4* dst = reinterpret_cast<float4*>(&a_l[j][n][0]);
    dst[0] = src[0]; dst[1] = src[1]; dst[2] = src[2]; dst[3] = src[3];
  }
  __syncthreads();

  // phase A: per-edge scores, leaky-relu
  for (int idx = tid; idx < EP_ * 16; idx += 256) {
    int e = idx >> 4, t = idx & 15;
    int s = eS[e], d = eD[e];
    float4 v;
    v.x = a_l[0][s][t] + a_l[4][d][t];
    v.y = a_l[1][s][t] + a_l[5][d][t];
    v.z = a_l[2][s][t] + a_l[6][d][t];
    v.w = a_l[3][s][t] + a_l[7][d][t];
    v.x = v.x > 0.f ? v.x : NEG_SLOPE * v.x;
    v.y = v.y > 0.f ? v.y : NEG_SLOPE * v.y;
    v.z = v.z > 0.f ? v.z : NEG_SLOPE * v.z;
    v.w = v.w > 0.f ? v.w : NEG_SLOPE * v.w;
    sc[e][t] = v;
  }
  __syncthreads();

  // phase B: per (dst,t) softmax over in-edges; rescale in place (owner-writes)
  for (int idx = tid; idx < N_ * 16; idx += 256) {
    int nd = idx >> 4, t = idx & 15;
    int e0 = iOff[nd], e1 = iOff[nd + 1];
    float m0 = -1e30f, m1 = -1e30f, m2 = -1e30f, m3 = -1e30f;
    for (int e = e0; e < e1; ++e) {
      float4 v = sc[iEid[e]][t];
      m0 = fmaxf(m0, v.x); m1 = fmaxf(m1, v.y);
      m2 = fmaxf(m2, v.z); m3 = fmaxf(m3, v.w);
    }
    float d0 = 0.f, d1 = 0.f, d2 = 0.f, d3 = 0.f;
    for (int e = e0; e < e1; ++e) {
      float4 v = sc[iEid[e]][t];
      d0 += __expf(v.x - m0); d1 += __expf(v.y - m1);
      d2 += __expf(v.z - m2); d3 += __expf(v.w - m3);
    }
    float i0 = 1.f / (d0 * (float)N_);   // fold mean-over-nodes 1/N
    float i1 = 1.f / (d1 * (float)N_);
    float i2 = 1.f / (d2 * (float)N_);
    float i3 = 1.f / (d3 * (float)N_);
    for (int e = e0; e < e1; ++e) {
      int ee = iEid[e];
      float4 v = sc[ee][t];
      v.x = __expf(v.x - m0) * i0; v.y = __expf(v.y - m1) * i1;
      v.z = __expf(v.z - m2) * i2; v.w = __expf(v.w - m3) * i3;
      sc[ee][t] = v;
    }
  }
  __syncthreads();

  // phase C: gather alpha by src -> w_l[n][h][t]
  for (int idx = tid; idx < N_ * 16; idx += 256) {
    int s = idx >> 4, t = idx & 15;
    int e0 = oOff[s], e1 = oOff[s + 1];
    float4 acc = {0.f, 0.f, 0.f, 0.f};
    for (int e = e0; e < e1; ++e) {
      float4 v = sc[oEid[e]][t];
      acc.x += v.x; acc.y += v.y; acc.z += v.z; acc.w += v.w;
    }
    w_l[s * 64 +  0 + t] = acc.x;
    w_l[s * 64 + 16 + t] = acc.y;
    w_l[s * 64 + 32 + t] = acc.z;
    w_l[s * 64 + 48 + t] = acc.w;
  }
  __syncthreads();

  // store w[b][n][h][t0..t0+15]
  const float4* wl4 = reinterpret_cast<const float4*>(w_l);
  for (int i = tid; i < 1024; i += 256) {
    int base = i * 4;
    int s = base >> 6;
    int rem = base & 63;
    int h = rem >> 4;
    int tt = rem & 15;
    *reinterpret_cast<float4*>(
        w_ws + ((size_t)(b * N_ + s) * H_ + h) * T_ + t0 + tt) = wl4[i];
  }
}

// ---- kernel B2: y[b][h][c][t] = sum_n w[b][n][h][t] * x[b][c][n][t] ------------
// grid = 512 (b = blk>>6, c-pair = blk&63), block = 256; all loads 1 KB
// contiguous float4 per wave; x re-read L3-served.
__global__ __launch_bounds__(256, 2)
void agg_kernel(const float* __restrict__ x,
                const float* __restrict__ w_ws,
                float* __restrict__ y_ws) {
  const int bid = blockIdx.x;
  const int b = bid >> 6;
  const int cp = bid & 63;
  const int tid = threadIdx.x;
  const int cl = tid >> 7, t4 = tid & 127;
  const int c = cp * 2 + cl;
  const float* xp = x + ((size_t)(b * C_ + c) * N_) * T_ + t4 * 4;
  const float* wp = w_ws + ((size_t)b * N_ * H_) * T_ + t4 * 4;
  float4 y0 = {0,0,0,0}, y1 = {0,0,0,0}, y2 = {0,0,0,0}, y3 = {0,0,0,0};
#pragma unroll 2
  for (int n = 0; n < N_; ++n) {
    float4 xv = *reinterpret_cast<const float4*>(xp + (size_t)n * T_);
    float4 w0 = *reinterpret_cast<const float4*>(wp + (size_t)(n * 4 + 0) * T_);
    float4 w1 = *reinterpret_cast<const float4*>(wp + (size_t)(n * 4 + 1) * T_);
    float4 w2 = *reinterpret_cast<const float4*>(wp + (size_t)(n * 4 + 2) * T_);
    float4 w3 = *reinterpret_cast<const float4*>(wp + (size_t)(n * 4 + 3) * T_);
    y0.x = fmaf(xv.x, w0.x, y0.x); y0.y = fmaf(xv.y, w0.y, y0.y);
    y0.z = fmaf(xv.z, w0.z, y0.z); y0.w = fmaf(xv.w, w0.w, y0.w);
    y1.x = fmaf(xv.x, w1.x, y1.x); y1.y = fmaf(xv.y, w1.y, y1.y);
    y1.z = fmaf(xv.z, w1.z, y1.z); y1.w = fmaf(xv.w, w1.w, y1.w);
    y2.x = fmaf(xv.x, w2.x, y2.x); y2.y = fmaf(xv.y, w2.y, y2.y);
    y2.z = fmaf(xv.z, w2.z, y2.z); y2.w = fmaf(xv.w, w2.w, y2.w);
    y3.x = fmaf(xv.x, w3.x, y3.x); y3.y = fmaf(xv.y, w3.y, y3.y);
    y3.z = fmaf(xv.z, w3.z, y3.z); y3.w = fmaf(xv.w, w3.w, y3.w);
  }
  size_t yb = ((size_t)(b * H_) * C_ + c) * T_ + t4 * 4;
  const size_t hs = (size_t)C_ * T_;
  *reinterpret_cast<float4*>(y_ws + yb)          = y0;
  *reinterpret_cast<float4*>(y_ws + yb + hs)     = y1;
  *reinterpret_cast<float4*>(y_ws + yb + 2 * hs) = y2;
  *reinterpret_cast<float4*>(y_ws + yb + 3 * hs) = y3;
}

// ---- kernel B3: out = BN(y·W + bias) -------------------------------------------
// grid = B*H*(T/64) = 256, block = 256
__global__ void out_kernel(const float* __restrict__ y_ws,
                           const float* __restrict__ W,
                           const float* __restrict__ bias,
                           const float* __restrict__ bn_gamma,
                           const float* __restrict__ bn_beta,
                           const float* __restrict__ bn_mean,
                           const float* __restrict__ bn_var,
                           float* __restrict__ out) {
  __shared__ float wl[C_ * D_];   // W[:,h,:] 16 KB
  int blk = blockIdx.x;
  int b = blk & 7;
  int h = (blk >> 3) & 3;
  int tcb = blk >> 5;
  int tid = threadIdx.x;
  int t = tcb * 64 + (tid & 63);
  int d0 = (tid >> 6) * 8;
  for (int i = tid; i < C_ * D_; i += 256) {
    int c = i >> 5, d = i & 31;
    wl[i] = W[((size_t)c * H_ + h) * D_ + d];
  }
  __syncthreads();
  float acc[8] = {0.f, 0.f, 0.f, 0.f, 0.f, 0.f, 0.f, 0.f};
  const float* yp = y_ws + ((size_t)b * H_ + h) * C_ * T_ + t;
#pragma unroll 4
  for (int c = 0; c < C_; ++c) {
    float yv = yp[(size_t)c * T_];
    const float4 w0 = *reinterpret_cast<const float4*>(&wl[c * D_ + d0]);
    const float4 w1 = *reinterpret_cast<const float4*>(&wl[c * D_ + d0 + 4]);
    acc[0] = fmaf(yv, w0.x, acc[0]); acc[1] = fmaf(yv, w0.y, acc[1]);
    acc[2] = fmaf(yv, w0.z, acc[2]); acc[3] = fmaf(yv, w0.w, acc[3]);
    acc[4] = fmaf(yv, w1.x, acc[4]); acc[5] = fmaf(yv, w1.y, acc[5]);
    acc[6] = fmaf(yv, w1.z, acc[6]); acc[7] = fmaf(yv, w1.w, acc[7]);
  }
#pragma unroll
  for (int k = 0; k < 8; ++k) {
    int oc = h * D_ + d0 + k;
    float scale = bn_gamma[oc] * rsqrtf(bn_var[oc] + BN_EPS);
    float shift = bn_beta[oc] - bn_mean[oc] * scale;
    out[((size_t)b * OUT_ + oc) * T_ + t] = (acc[k] + bias[oc]) * scale + shift;
  }
}

extern "C" void kernel_launch(void* const* d_in, const int* in_sizes, int n_in,
                              void* d_out, int out_size, void* d_ws, size_t ws_size,
                              hipStream_t stream) {
  const float* x        = (const float*)d_in[0];
  const float* W        = (const float*)d_in[1];
  const float* att_src  = (const float*)d_in[2];
  const float* att_dst  = (const float*)d_in[3];
  const float* bias     = (const float*)d_in[4];
  const float* bn_gamma = (const float*)d_in[5];
  const float* bn_beta  = (const float*)d_in[6];
  const float* bn_mean  = (const float*)d_in[7];
  const float* bn_var   = (const float*)d_in[8];
  const int* edge_index = (const int*)d_in[9];
  float* out = (float*)d_out;

  char* ws = (char*)d_ws;
  float* wa    = (float*)ws;                  // 4 KB
  int* esrc_g  = (int*)(ws + 4096);
  int* edst_g  = (int*)(ws + 6144);
  int* iOff_g  = (int*)(ws + 8192);
  int* iEid_g  = (int*)(ws + 8704);
  int* oOff_g  = (int*)(ws + 10752);
  int* oEid_g  = (int*)(ws + 11264);
  float* a_ws  = (float*)(ws + 16384);        // 8 MB  [b][n][j][t]
  float* y_ws  = a_ws;                        // 8 MB  [b][h][c][t] (aliases a; a dead after weights)
  float* w_ws  = (float*)(ws + 16384 + (size_t)8 * 1024 * 1024);  // 4 MB [b][n][h][t]

  setup_kernel<<<1, 256, 0, stream>>>(W, att_src, att_dst, edge_index, wa,
                                      esrc_g, edst_g, iOff_g, iEid_g, oOff_g, oEid_g);
  proj_kernel<<<B_ * N_ * 2, 256, 0, stream>>>(x, wa, a_ws);
  weights_kernel<<<B_ * (T_ / 16), 256, 0, stream>>>(a_ws, esrc_g, edst_g,
                                                     iOff_g, iEid_g, oOff_g, oEid_g,
                                                     w_ws);
  agg_kernel<<<512, 256, 0, stream>>>(x, w_ws, y_ws);
  out_kernel<<<B_ * H_ * (T_ / 64), 256, 0, stream>>>(y_ws, W, bias, bn_gamma,
                                                      bn_beta, bn_mean, bn_var, out);
}

// Round 7
// 82.495 us; speedup vs baseline: 1.2802x; 1.2802x over previous
//
#include <hip/hip_runtime.h>
#include <math.h>

#define B_ 8
#define C_ 128
#define N_ 64
#define T_ 512
#define H_ 4
#define D_ 32
#define OUT_ 128
#define E_ 256
#define EP_ 320   // E + N self-loops
#define NEG_SLOPE 0.2f
#define BN_EPS 1e-5f
#define TC 8      // time steps per block

// ---- setup: wa[c][8] = W·att; in-list (src per in-edge, grouped by dst);
// ----        out-list (dst per out-edge, grouped by src)
__global__ void setup_kernel(const float* __restrict__ W,
                             const float* __restrict__ att_src,
                             const float* __restrict__ att_dst,
                             const int* __restrict__ edge_index,
                             float* __restrict__ wa,
                             int* __restrict__ iOff_g, int* __restrict__ iSrc_g,
                             int* __restrict__ oOff_g, int* __restrict__ oDst_g) {
  __shared__ int icnt[N_], ibase[N_ + 1], ifill[N_];
  __shared__ int ocnt[N_], obase[N_ + 1], ofill[N_];
  __shared__ int esrc[EP_], edst[EP_];
  int tid = threadIdx.x;

  for (int idx = tid; idx < C_ * 8; idx += blockDim.x) {
    int c = idx >> 3, j = idx & 7, h = j & 3;
    const float* att = (j < 4) ? att_src : att_dst;
    float s = 0.f;
    for (int d = 0; d < D_; ++d)
      s += W[(c * H_ + h) * D_ + d] * att[h * D_ + d];
    wa[idx] = s;
  }
  if (tid < N_) { icnt[tid] = 0; ifill[tid] = 0; ocnt[tid] = 0; ofill[tid] = 0; }
  __syncthreads();
  for (int e = tid; e < EP_; e += blockDim.x) {
    int s, d;
    if (e < E_) { s = edge_index[e]; d = edge_index[E_ + e]; }
    else        { s = e - E_;        d = e - E_; }
    esrc[e] = s; edst[e] = d;
    atomicAdd(&icnt[d], 1);
    atomicAdd(&ocnt[s], 1);
  }
  __syncthreads();
  if (tid == 0) {
    int ai = 0, ao = 0;
    for (int n = 0; n < N_; ++n) {
      ibase[n] = ai; ai += icnt[n];
      obase[n] = ao; ao += ocnt[n];
    }
    ibase[N_] = ai; obase[N_] = ao;
  }
  __syncthreads();
  if (tid <= N_) { iOff_g[tid] = ibase[tid]; oOff_g[tid] = obase[tid]; }
  for (int e = tid; e < EP_; e += blockDim.x) {
    int s = esrc[e], d = edst[e];
    int pi = ibase[d] + atomicAdd(&ifill[d], 1);
    iSrc_g[pi] = s;
    int po = obase[s] + atomicAdd(&ofill[s], 1);
    oDst_g[po] = d;
  }
}

#define P1FMA(J, WS) \
  acc[J].x = fmaf(xv[u].x, WS, acc[J].x); \
  acc[J].y = fmaf(xv[u].y, WS, acc[J].y); \
  acc[J].z = fmaf(xv[u].z, WS, acc[J].z); \
  acc[J].w = fmaf(xv[u].w, WS, acc[J].w);

// ---- megakernel: one block per (b, 8-t chunk). grid = 512 = 2 blocks/CU.
__global__ __launch_bounds__(256, 2)
void mega_kernel(const float* __restrict__ x,
                 const float* __restrict__ wa_g,
                 const float* __restrict__ W,
                 const int* __restrict__ iOff_g, const int* __restrict__ iSrc_g,
                 const int* __restrict__ oOff_g, const int* __restrict__ oDst_g,
                 const float* __restrict__ bias,
                 const float* __restrict__ bn_gamma,
                 const float* __restrict__ bn_beta,
                 const float* __restrict__ bn_mean,
                 const float* __restrict__ bn_var,
                 float* __restrict__ out) {
  __shared__ float a_l[8 * 64 * 12];   // [j][n][8+4pad] 24.6KB; y overlay [4][128][9]
  __shared__ float4 red4[8 * 128];     // c-parity partial reduce, 16 KB
  __shared__ float z_l[64 * 9 * 4];    // [(nd*9+t)*4+h] = exp(-m)/(den*N), 9.2 KB
  __shared__ float w_l[64 * 36];       // [n*36 + h*8 + t], 9.2 KB
  __shared__ float wal[C_ * 8];        // 4 KB
  __shared__ int iOff[N_ + 1], oOff[N_ + 1];
  __shared__ int iSrc[EP_], oDst[EP_];

  const int tid = threadIdx.x;
  const int b = blockIdx.x & 7;              // batch -> XCD pinning
  const int tchunk = blockIdx.x >> 3;        // 0..63
  const int t0 = tchunk * TC;

  for (int i = tid; i < EP_; i += 256) { iSrc[i] = iSrc_g[i]; oDst[i] = oDst_g[i]; }
  if (tid <= N_) { iOff[tid] = iOff_g[tid]; oOff[tid] = oOff_g[tid]; }
  for (int i = tid; i < C_ * 8; i += 256) wal[i] = wa_g[i];
  __syncthreads();

  // ---------------- pass 1: a[j][n][t] = sum_c x[b][c][n][t]*wa[c][j] ----------
  // waves 0-1: even c; waves 2-3: odd c. 8 float4 loads batched back-to-back.
  {
    const int cpar = __builtin_amdgcn_readfirstlane(tid >> 7);
    const int r = tid & 127;
    const int n1 = r >> 1, th = r & 1;       // thread: node n1, t = th*4..th*4+3
    const float* xp = x + ((size_t)(b * C_ + cpar) * N_ + n1) * T_ + t0 + th * 4;
    float4 acc[8];
#pragma unroll
    for (int j = 0; j < 8; ++j) { acc[j].x = 0.f; acc[j].y = 0.f; acc[j].z = 0.f; acc[j].w = 0.f; }
    for (int kb = 0; kb < 8; ++kb) {
      float4 xv[8];
#pragma unroll
      for (int u = 0; u < 8; ++u)
        xv[u] = *reinterpret_cast<const float4*>(xp + (size_t)(kb * 16 + u * 2) * (N_ * T_));
#pragma unroll
      for (int u = 0; u < 8; ++u) {
        const int c = cpar + (kb * 8 + u) * 2;
        const float4 w0 = *reinterpret_cast<const float4*>(&wal[c * 8]);
        const float4 w1 = *reinterpret_cast<const float4*>(&wal[c * 8 + 4]);
        P1FMA(0, w0.x) P1FMA(1, w0.y) P1FMA(2, w0.z) P1FMA(3, w0.w)
        P1FMA(4, w1.x) P1FMA(5, w1.y) P1FMA(6, w1.z) P1FMA(7, w1.w)
      }
    }
    if (cpar == 1) {
#pragma unroll
      for (int j = 0; j < 8; ++j) red4[j * 128 + r] = acc[j];
    }
    __syncthreads();
    if (cpar == 0) {
#pragma unroll
      for (int j = 0; j < 8; ++j) {
        float4 o = red4[j * 128 + r];
        float* ap = &a_l[j * 768 + n1 * 12 + th * 4];
        ap[0] = acc[j].x + o.x; ap[1] = acc[j].y + o.y;
        ap[2] = acc[j].z + o.z; ap[3] = acc[j].w + o.w;
      }
    }
    __syncthreads();
  }

  // ---------------- softmax phase B: per (dst,t): z = exp(-m)/(den*N) ----------
  {
    const int t = tid & 7, grp = tid >> 3;   // 8 t x 32 groups
#pragma unroll
    for (int rep = 0; rep < 2; ++rep) {
      int nd = grp + rep * 32;
      int e0 = iOff[nd], e1 = iOff[nd + 1];
      float ad0 = a_l[4 * 768 + nd * 12 + t];
      float ad1 = a_l[5 * 768 + nd * 12 + t];
      float ad2 = a_l[6 * 768 + nd * 12 + t];
      float ad3 = a_l[7 * 768 + nd * 12 + t];
      float m0 = -1e30f, m1 = -1e30f, m2 = -1e30f, m3 = -1e30f;
      for (int e = e0; e < e1; ++e) {
        int s = iSrc[e];
        float v0 = a_l[0 * 768 + s * 12 + t] + ad0; v0 = v0 > 0.f ? v0 : NEG_SLOPE * v0;
        float v1 = a_l[1 * 768 + s * 12 + t] + ad1; v1 = v1 > 0.f ? v1 : NEG_SLOPE * v1;
        float v2 = a_l[2 * 768 + s * 12 + t] + ad2; v2 = v2 > 0.f ? v2 : NEG_SLOPE * v2;
        float v3 = a_l[3 * 768 + s * 12 + t] + ad3; v3 = v3 > 0.f ? v3 : NEG_SLOPE * v3;
        m0 = fmaxf(m0, v0); m1 = fmaxf(m1, v1);
        m2 = fmaxf(m2, v2); m3 = fmaxf(m3, v3);
      }
      float d0 = 0.f, d1 = 0.f, d2 = 0.f, d3 = 0.f;
      for (int e = e0; e < e1; ++e) {
        int s = iSrc[e];
        float v0 = a_l[0 * 768 + s * 12 + t] + ad0; v0 = v0 > 0.f ? v0 : NEG_SLOPE * v0;
        float v1 = a_l[1 * 768 + s * 12 + t] + ad1; v1 = v1 > 0.f ? v1 : NEG_SLOPE * v1;
        float v2 = a_l[2 * 768 + s * 12 + t] + ad2; v2 = v2 > 0.f ? v2 : NEG_SLOPE * v2;
        float v3 = a_l[3 * 768 + s * 12 + t] + ad3; v3 = v3 > 0.f ? v3 : NEG_SLOPE * v3;
        d0 += __expf(v0 - m0); d1 += __expf(v1 - m1);
        d2 += __expf(v2 - m2); d3 += __expf(v3 - m3);
      }
      float4 zv;
      zv.x = __expf(-m0) / (d0 * (float)N_);
      zv.y = __expf(-m1) / (d1 * (float)N_);
      zv.z = __expf(-m2) / (d2 * (float)N_);
      zv.w = __expf(-m3) / (d3 * (float)N_);
      *reinterpret_cast<float4*>(&z_l[(nd * 9 + t) * 4]) = zv;
    }
  }
  __syncthreads();

  // ---------------- softmax phase C: per (src,t) gather -> w[n][h][t] ----------
  {
    const int t = tid & 7, grp = tid >> 3;
#pragma unroll
    for (int rep = 0; rep < 2; ++rep) {
      int src = grp + rep * 32;
      int e0 = oOff[src], e1 = oOff[src + 1];
      float as0 = a_l[0 * 768 + src * 12 + t];
      float as1 = a_l[1 * 768 + src * 12 + t];
      float as2 = a_l[2 * 768 + src * 12 + t];
      float as3 = a_l[3 * 768 + src * 12 + t];
      float w0 = 0.f, w1 = 0.f, w2 = 0.f, w3 = 0.f;
      for (int e = e0; e < e1; ++e) {
        int d = oDst[e];
        float4 zv = *reinterpret_cast<const float4*>(&z_l[(d * 9 + t) * 4]);
        float v0 = as0 + a_l[4 * 768 + d * 12 + t]; v0 = v0 > 0.f ? v0 : NEG_SLOPE * v0;
        float v1 = as1 + a_l[5 * 768 + d * 12 + t]; v1 = v1 > 0.f ? v1 : NEG_SLOPE * v1;
        float v2 = as2 + a_l[6 * 768 + d * 12 + t]; v2 = v2 > 0.f ? v2 : NEG_SLOPE * v2;
        float v3 = as3 + a_l[7 * 768 + d * 12 + t]; v3 = v3 > 0.f ? v3 : NEG_SLOPE * v3;
        w0 += __expf(v0) * zv.x;
        w1 += __expf(v1) * zv.y;
        w2 += __expf(v2) * zv.z;
        w3 += __expf(v3) * zv.w;
      }
      w_l[src * 36 +  0 + t] = w0;
      w_l[src * 36 +  8 + t] = w1;
      w_l[src * 36 + 16 + t] = w2;
      w_l[src * 36 + 24 + t] = w3;
    }
  }
  __syncthreads();

  // ---------------- pass 2: y[h][c][t] = sum_n w[n][h][t] * x[b][c][n][t] ------
  // (x re-read: L2/L3-served). 8 float4 loads batched back-to-back.
  {
    const int cl = tid >> 1, g = tid & 1;    // c = cl; t = g*4 .. g*4+3
    const float* xb = x + ((size_t)(b * C_) + cl) * N_ * T_ + t0 + g * 4;
    float4 yr[4];
#pragma unroll
    for (int h = 0; h < 4; ++h) { yr[h].x = 0.f; yr[h].y = 0.f; yr[h].z = 0.f; yr[h].w = 0.f; }
    for (int nb = 0; nb < 8; ++nb) {
      float4 xv[8];
#pragma unroll
      for (int u = 0; u < 8; ++u)
        xv[u] = *reinterpret_cast<const float4*>(xb + (size_t)(nb * 8 + u) * T_);
#pragma unroll
      for (int u = 0; u < 8; ++u) {
        const int n = nb * 8 + u;
#pragma unroll
        for (int h = 0; h < 4; ++h) {
          float4 wv = *reinterpret_cast<const float4*>(&w_l[n * 36 + h * 8 + g * 4]);
          yr[h].x = fmaf(xv[u].x, wv.x, yr[h].x);
          yr[h].y = fmaf(xv[u].y, wv.y, yr[h].y);
          yr[h].z = fmaf(xv[u].z, wv.z, yr[h].z);
          yr[h].w = fmaf(xv[u].w, wv.w, yr[h].w);
        }
      }
    }
    float* y_l = a_l;                         // overlay (a dead after phase C)
#pragma unroll
    for (int h = 0; h < 4; ++h) {
      y_l[h * 1152 + cl * 9 + g * 4 + 0] = yr[h].x;
      y_l[h * 1152 + cl * 9 + g * 4 + 1] = yr[h].y;
      y_l[h * 1152 + cl * 9 + g * 4 + 2] = yr[h].z;
      y_l[h * 1152 + cl * 9 + g * 4 + 3] = yr[h].w;
    }
  }
  __syncthreads();

  // ---------------- pass 3: out[oc][t] = BN(sum_c y[h][c][t]*W[c][h][d] + bias)
  {
    const int t3 = tid & 7, g3 = tid >> 3;   // g3 0..31
    const int h = g3 >> 3, d0 = (g3 & 7) * 4;
    const float* y_l = a_l;
    float acc[4] = {0.f, 0.f, 0.f, 0.f};
#pragma unroll 4
    for (int c = 0; c < C_; ++c) {
      float yv = y_l[h * 1152 + c * 9 + t3];
      const float4 wv = *reinterpret_cast<const float4*>(
          &W[((size_t)c * H_ + h) * D_ + d0]);
      acc[0] = fmaf(yv, wv.x, acc[0]); acc[1] = fmaf(yv, wv.y, acc[1]);
      acc[2] = fmaf(yv, wv.z, acc[2]); acc[3] = fmaf(yv, wv.w, acc[3]);
    }
#pragma unroll
    for (int k = 0; k < 4; ++k) {
      int oc = h * D_ + d0 + k;
      float scale = bn_gamma[oc] * rsqrtf(bn_var[oc] + BN_EPS);
      float shift = bn_beta[oc] - bn_mean[oc] * scale;
      out[((size_t)b * OUT_ + oc) * T_ + t0 + t3] =
          (acc[k] + bias[oc]) * scale + shift;
    }
  }
}

extern "C" void kernel_launch(void* const* d_in, const int* in_sizes, int n_in,
                              void* d_out, int out_size, void* d_ws, size_t ws_size,
                              hipStream_t stream) {
  const float* x        = (const float*)d_in[0];
  const float* W        = (const float*)d_in[1];
  const float* att_src  = (const float*)d_in[2];
  const float* att_dst  = (const float*)d_in[3];
  const float* bias     = (const float*)d_in[4];
  const float* bn_gamma = (const float*)d_in[5];
  const float* bn_beta  = (const float*)d_in[6];
  const float* bn_mean  = (const float*)d_in[7];
  const float* bn_var   = (const float*)d_in[8];
  const int* edge_index = (const int*)d_in[9];
  float* out = (float*)d_out;

  char* ws = (char*)d_ws;
  float* wa   = (float*)ws;            // 4 KB
  int* iOff_g = (int*)(ws + 4096);     // 65 ints
  int* iSrc_g = (int*)(ws + 4608);     // 320 ints
  int* oOff_g = (int*)(ws + 6144);     // 65 ints
  int* oDst_g = (int*)(ws + 6656);     // 320 ints

  setup_kernel<<<1, 256, 0, stream>>>(W, att_src, att_dst, edge_index, wa,
                                      iOff_g, iSrc_g, oOff_g, oDst_g);
  mega_kernel<<<512, 256, 0, stream>>>(x, wa, W, iOff_g, iSrc_g, oOff_g, oDst_g,
                                       bias, bn_gamma, bn_beta, bn_mean, bn_var,
                                       out);
}